// Round 1
// baseline (8522.734 us; speedup 1.0000x reference)
//
#include <hip/hip_runtime.h>
#include <hip/hip_bf16.h>
#include <math.h>

#define N_NODES 100000
#define N_EDGES 1600000
#define D_IN    384
#define D_HID   768
#define D_OUT   256

// ---------------------------------------------------------------------------
// K1: fused encoder: H = (GELU(LN(X @ W1 + b1)) ) @ W2 + b2
// 16 rows per block, 256 threads. LDS holds X-tile and H1-tile transposed
// ([col][row], row stride 16 floats) so the inner K loops read broadcast
// float4s while W streams coalesced from L2 (W1+W2 = 1.95 MB, fits per-XCD L2).
// ---------------------------------------------------------------------------
__global__ __launch_bounds__(256) void encoder_kernel(
    const float* __restrict__ X, const float* __restrict__ W1,
    const float* __restrict__ b1, const float* __restrict__ g1,
    const float* __restrict__ be1, const float* __restrict__ W2,
    const float* __restrict__ b2, float* __restrict__ H)
{
    __shared__ float Xt[D_IN * 16];    // [k][r], stride 16
    __shared__ float H1t[D_HID * 16];  // [c][r], stride 16
    const int t = threadIdx.x;
    const int row0 = blockIdx.x * 16;

    // load 16 contiguous rows of X (16*384 floats) -> transposed LDS
    const float4* X4 = (const float4*)(X + (size_t)row0 * D_IN);
    for (int i = t; i < 16 * 96; i += 256) {
        int r = i / 96, c4 = i % 96;
        float4 v = X4[i];
        int cb = c4 * 4;
        Xt[(cb + 0) * 16 + r] = v.x;
        Xt[(cb + 1) * 16 + r] = v.y;
        Xt[(cb + 2) * 16 + r] = v.z;
        Xt[(cb + 3) * 16 + r] = v.w;
    }
    __syncthreads();

    // phase 1: H1 = X @ W1 + b1 ; thread t owns cols {t, t+256, t+512}
    float acc0[16], acc1[16], acc2[16];
    {
        float b1v0 = b1[t], b1v1 = b1[t + 256], b1v2 = b1[t + 512];
        #pragma unroll
        for (int r = 0; r < 16; ++r) { acc0[r] = b1v0; acc1[r] = b1v1; acc2[r] = b1v2; }
    }
    #pragma unroll 2
    for (int k = 0; k < D_IN; ++k) {
        float w0 = W1[k * D_HID + t];
        float w1 = W1[k * D_HID + t + 256];
        float w2 = W1[k * D_HID + t + 512];
        const float4* xp = (const float4*)&Xt[k * 16];
        float4 xa = xp[0], xb = xp[1], xc = xp[2], xd = xp[3];
        float xs[16];
        xs[0]=xa.x; xs[1]=xa.y; xs[2]=xa.z; xs[3]=xa.w;
        xs[4]=xb.x; xs[5]=xb.y; xs[6]=xb.z; xs[7]=xb.w;
        xs[8]=xc.x; xs[9]=xc.y; xs[10]=xc.z; xs[11]=xc.w;
        xs[12]=xd.x; xs[13]=xd.y; xs[14]=xd.z; xs[15]=xd.w;
        #pragma unroll
        for (int r = 0; r < 16; ++r) {
            acc0[r] += xs[r] * w0;
            acc1[r] += xs[r] * w1;
            acc2[r] += xs[r] * w2;
        }
    }
    #pragma unroll
    for (int r = 0; r < 16; ++r) {
        H1t[(t      ) * 16 + r] = acc0[r];
        H1t[(t + 256) * 16 + r] = acc1[r];
        H1t[(t + 512) * 16 + r] = acc2[r];
    }
    __syncthreads();

    // phase 2: LayerNorm(768) + exact GELU, in LDS.
    // wave w handles rows 4w..4w+3 concurrently: lane -> (r = lane>>4, k0 = lane&15)
    {
        const int lane = t & 63, wv = t >> 6;
        const int r = wv * 4 + (lane >> 4);
        const int k0 = lane & 15;
        float vals[48];
        float s = 0.f, s2 = 0.f;
        #pragma unroll
        for (int j = 0; j < 48; ++j) {
            float v = H1t[(k0 + 16 * j) * 16 + r];
            vals[j] = v; s += v; s2 += v * v;
        }
        // reduce across the 16 lanes sharing row r (xor 1,2,4,8)
        #pragma unroll
        for (int m = 1; m <= 8; m <<= 1) {
            s  += __shfl_xor(s,  m, 64);
            s2 += __shfl_xor(s2, m, 64);
        }
        float mu   = s / 768.f;
        float var  = s2 / 768.f - mu * mu;
        float rstd = rsqrtf(var + 1e-5f);
        #pragma unroll
        for (int j = 0; j < 48; ++j) {
            int k = k0 + 16 * j;
            float v = (vals[j] - mu) * rstd * g1[k] + be1[k];
            v = 0.5f * v * (1.0f + erff(v * 0.70710678118654752f)); // exact gelu
            H1t[k * 16 + r] = v;
        }
    }
    __syncthreads();

    // phase 3: H = H1g @ W2 + b2 ; thread t owns col t, rows 0..15
    float acc[16];
    {
        float b2v = b2[t];
        #pragma unroll
        for (int r = 0; r < 16; ++r) acc[r] = b2v;
    }
    #pragma unroll 2
    for (int k = 0; k < D_HID; ++k) {
        float w = W2[k * D_OUT + t];
        const float4* hp = (const float4*)&H1t[k * 16];
        float4 ha = hp[0], hb = hp[1], hc = hp[2], hd = hp[3];
        float hs[16];
        hs[0]=ha.x; hs[1]=ha.y; hs[2]=ha.z; hs[3]=ha.w;
        hs[4]=hb.x; hs[5]=hb.y; hs[6]=hb.z; hs[7]=hb.w;
        hs[8]=hc.x; hs[9]=hc.y; hs[10]=hc.z; hs[11]=hc.w;
        hs[12]=hd.x; hs[13]=hd.y; hs[14]=hd.z; hs[15]=hd.w;
        #pragma unroll
        for (int r = 0; r < 16; ++r) acc[r] += hs[r] * w;
    }
    #pragma unroll
    for (int r = 0; r < 16; ++r)
        H[(size_t)(row0 + r) * D_OUT + t] = acc[r];
}

// ---------------------------------------------------------------------------
// K2: SAGE mean-aggregation numerator: one wave per edge, lane = 4 dims.
// summed (= d_out) and cnt must be pre-zeroed.
// ---------------------------------------------------------------------------
__global__ __launch_bounds__(256) void scatter_kernel(
    const int* __restrict__ edges, const float* __restrict__ H,
    float* __restrict__ summed, float* __restrict__ cnt)
{
    int e = blockIdx.x * 4 + (threadIdx.x >> 6);
    if (e >= N_EDGES) return;
    int lane = threadIdx.x & 63;
    int s = edges[e];
    int d = edges[N_EDGES + e];
    float4 hv = ((const float4*)H)[(size_t)s * 64 + lane];
    float* dst = summed + (size_t)d * D_OUT + lane * 4;
    atomicAdd(dst + 0, hv.x);
    atomicAdd(dst + 1, hv.y);
    atomicAdd(dst + 2, hv.z);
    atomicAdd(dst + 3, hv.w);
    if (lane == 0) atomicAdd(cnt + d, 1.0f);
}

// ---------------------------------------------------------------------------
// K3: finalize: mean = summed/max(cnt,1); sage = mean@Wl + bl + h@Wr;
//     out = LN(h + sage) * g2 + be2. In-place on d_out (summed).
// 16 rows per block, 256 threads; thread t owns output col t.
// ---------------------------------------------------------------------------
__global__ __launch_bounds__(256) void finalize_kernel(
    const float* __restrict__ H, const float* __restrict__ cnt,
    const float* __restrict__ Wl, const float* __restrict__ bl,
    const float* __restrict__ Wr, const float* __restrict__ g2,
    const float* __restrict__ be2, float* __restrict__ out)
{
    __shared__ float mt[D_OUT * 16];   // mean, [k][r] stride 16
    __shared__ float ht[D_OUT * 16];   // h,    [k][r] stride 16
    __shared__ float red[16 * 4 * 2];  // per-row per-wave partial (sum, sumsq)
    const int t = threadIdx.x;
    const int row0 = blockIdx.x * 16;

    const float4* S4 = (const float4*)(out + (size_t)row0 * D_OUT);
    const float4* H4 = (const float4*)(H + (size_t)row0 * D_OUT);
    for (int i = t; i < 16 * 64; i += 256) {
        int r = i >> 6, c4 = i & 63;
        float inv = 1.0f / fmaxf(cnt[row0 + r], 1.0f);
        float4 sv = S4[i];
        float4 hv = H4[i];
        int cb = c4 * 4;
        mt[(cb + 0) * 16 + r] = sv.x * inv;
        mt[(cb + 1) * 16 + r] = sv.y * inv;
        mt[(cb + 2) * 16 + r] = sv.z * inv;
        mt[(cb + 3) * 16 + r] = sv.w * inv;
        ht[(cb + 0) * 16 + r] = hv.x;
        ht[(cb + 1) * 16 + r] = hv.y;
        ht[(cb + 2) * 16 + r] = hv.z;
        ht[(cb + 3) * 16 + r] = hv.w;
    }
    __syncthreads();

    float acc[16];
    {
        float blv = bl[t];
        #pragma unroll
        for (int r = 0; r < 16; ++r) acc[r] = blv;
    }
    #pragma unroll 2
    for (int k = 0; k < D_OUT; ++k) {
        float wl = Wl[k * D_OUT + t];
        float wr = Wr[k * D_OUT + t];
        const float4* mp = (const float4*)&mt[k * 16];
        const float4* hp = (const float4*)&ht[k * 16];
        float4 ma = mp[0], mb = mp[1], mc = mp[2], md = mp[3];
        float4 ha = hp[0], hb = hp[1], hc = hp[2], hd = hp[3];
        float ms[16], hs[16];
        ms[0]=ma.x; ms[1]=ma.y; ms[2]=ma.z; ms[3]=ma.w;
        ms[4]=mb.x; ms[5]=mb.y; ms[6]=mb.z; ms[7]=mb.w;
        ms[8]=mc.x; ms[9]=mc.y; ms[10]=mc.z; ms[11]=mc.w;
        ms[12]=md.x; ms[13]=md.y; ms[14]=md.z; ms[15]=md.w;
        hs[0]=ha.x; hs[1]=ha.y; hs[2]=ha.z; hs[3]=ha.w;
        hs[4]=hb.x; hs[5]=hb.y; hs[6]=hb.z; hs[7]=hb.w;
        hs[8]=hc.x; hs[9]=hc.y; hs[10]=hc.z; hs[11]=hc.w;
        hs[12]=hd.x; hs[13]=hd.y; hs[14]=hd.z; hs[15]=hd.w;
        #pragma unroll
        for (int r = 0; r < 16; ++r) acc[r] += ms[r] * wl + hs[r] * wr;
    }

    // y = h + sage
    float y[16];
    #pragma unroll
    for (int r = 0; r < 16; ++r) y[r] = ht[t * 16 + r] + acc[r];

    // per-row LayerNorm stats across the 256 threads (each holds one col)
    const int lane = t & 63, wv = t >> 6;
    #pragma unroll
    for (int r = 0; r < 16; ++r) {
        float s = y[r], s2 = y[r] * y[r];
        #pragma unroll
        for (int m = 1; m <= 32; m <<= 1) {
            s  += __shfl_xor(s,  m, 64);
            s2 += __shfl_xor(s2, m, 64);
        }
        if (lane == 0) { red[r * 8 + wv * 2] = s; red[r * 8 + wv * 2 + 1] = s2; }
    }
    __syncthreads();

    #pragma unroll
    for (int r = 0; r < 16; ++r) {
        float ssum  = red[r * 8 + 0] + red[r * 8 + 2] + red[r * 8 + 4] + red[r * 8 + 6];
        float ssum2 = red[r * 8 + 1] + red[r * 8 + 3] + red[r * 8 + 5] + red[r * 8 + 7];
        float mu   = ssum / 256.f;
        float var  = ssum2 / 256.f - mu * mu;
        float rstd = rsqrtf(var + 1e-5f);
        out[(size_t)(row0 + r) * D_OUT + t] = (y[r] - mu) * rstd * g2[t] + be2[t];
    }
}

extern "C" void kernel_launch(void* const* d_in, const int* in_sizes, int n_in,
                              void* d_out, int out_size, void* d_ws, size_t ws_size,
                              hipStream_t stream)
{
    const float* X   = (const float*)d_in[0];
    const int*   edg = (const int*)  d_in[1];
    const float* W1  = (const float*)d_in[2];
    const float* b1  = (const float*)d_in[3];
    const float* g1  = (const float*)d_in[4];
    const float* be1 = (const float*)d_in[5];
    const float* W2  = (const float*)d_in[6];
    const float* b2  = (const float*)d_in[7];
    const float* Wl  = (const float*)d_in[8];
    const float* bl  = (const float*)d_in[9];
    const float* Wr  = (const float*)d_in[10];
    const float* g2  = (const float*)d_in[11];
    const float* be2 = (const float*)d_in[12];

    float* out = (float*)d_out;
    float* H   = (float*)d_ws;                          // 100000*256 fp32 = 102.4 MB
    float* cnt = (float*)d_ws + (size_t)N_NODES * D_OUT; // 100000 fp32

    // summed (= d_out) and cnt must start at zero every call (ws is re-poisoned)
    hipMemsetAsync(d_out, 0, (size_t)N_NODES * D_OUT * sizeof(float), stream);
    hipMemsetAsync(cnt, 0, (size_t)N_NODES * sizeof(float), stream);

    encoder_kernel<<<N_NODES / 16, 256, 0, stream>>>(X, W1, b1, g1, be1, W2, b2, H);
    scatter_kernel<<<N_EDGES / 4, 256, 0, stream>>>(edg, H, out, cnt);
    finalize_kernel<<<N_NODES / 16, 256, 0, stream>>>(H, cnt, Wl, bl, Wr, g2, be2, out);
}

// Round 2
// 3456.137 us; speedup vs baseline: 2.4660x; 2.4660x over previous
//
#include <hip/hip_runtime.h>
#include <hip/hip_bf16.h>
#include <math.h>

#define N_NODES 100000
#define N_EDGES 1600000
#define D_IN    384
#define D_HID   768
#define D_OUT   256

// ---------------------------------------------------------------------------
// K1: fused encoder: H = (GELU(LN(X @ W1 + b1)) ) @ W2 + b2
// 16 rows per block, 256 threads. LDS holds X-tile and H1-tile transposed
// ([col][row], row stride 16 floats) so the inner K loops read broadcast
// float4s while W streams coalesced from L2 (W1+W2 = 1.95 MB, fits per-XCD L2).
// ---------------------------------------------------------------------------
__global__ __launch_bounds__(256) void encoder_kernel(
    const float* __restrict__ X, const float* __restrict__ W1,
    const float* __restrict__ b1, const float* __restrict__ g1,
    const float* __restrict__ be1, const float* __restrict__ W2,
    const float* __restrict__ b2, float* __restrict__ H)
{
    __shared__ float Xt[D_IN * 16];    // [k][r], stride 16
    __shared__ float H1t[D_HID * 16];  // [c][r], stride 16
    const int t = threadIdx.x;
    const int row0 = blockIdx.x * 16;

    // load 16 contiguous rows of X (16*384 floats) -> transposed LDS
    const float4* X4 = (const float4*)(X + (size_t)row0 * D_IN);
    for (int i = t; i < 16 * 96; i += 256) {
        int r = i / 96, c4 = i % 96;
        float4 v = X4[i];
        int cb = c4 * 4;
        Xt[(cb + 0) * 16 + r] = v.x;
        Xt[(cb + 1) * 16 + r] = v.y;
        Xt[(cb + 2) * 16 + r] = v.z;
        Xt[(cb + 3) * 16 + r] = v.w;
    }
    __syncthreads();

    // phase 1: H1 = X @ W1 + b1 ; thread t owns cols {t, t+256, t+512}
    float acc0[16], acc1[16], acc2[16];
    {
        float b1v0 = b1[t], b1v1 = b1[t + 256], b1v2 = b1[t + 512];
        #pragma unroll
        for (int r = 0; r < 16; ++r) { acc0[r] = b1v0; acc1[r] = b1v1; acc2[r] = b1v2; }
    }
    #pragma unroll 2
    for (int k = 0; k < D_IN; ++k) {
        float w0 = W1[k * D_HID + t];
        float w1 = W1[k * D_HID + t + 256];
        float w2 = W1[k * D_HID + t + 512];
        const float4* xp = (const float4*)&Xt[k * 16];
        float4 xa = xp[0], xb = xp[1], xc = xp[2], xd = xp[3];
        float xs[16];
        xs[0]=xa.x; xs[1]=xa.y; xs[2]=xa.z; xs[3]=xa.w;
        xs[4]=xb.x; xs[5]=xb.y; xs[6]=xb.z; xs[7]=xb.w;
        xs[8]=xc.x; xs[9]=xc.y; xs[10]=xc.z; xs[11]=xc.w;
        xs[12]=xd.x; xs[13]=xd.y; xs[14]=xd.z; xs[15]=xd.w;
        #pragma unroll
        for (int r = 0; r < 16; ++r) {
            acc0[r] += xs[r] * w0;
            acc1[r] += xs[r] * w1;
            acc2[r] += xs[r] * w2;
        }
    }
    #pragma unroll
    for (int r = 0; r < 16; ++r) {
        H1t[(t      ) * 16 + r] = acc0[r];
        H1t[(t + 256) * 16 + r] = acc1[r];
        H1t[(t + 512) * 16 + r] = acc2[r];
    }
    __syncthreads();

    // phase 2: LayerNorm(768) + exact GELU, in LDS.
    {
        const int lane = t & 63, wv = t >> 6;
        const int r = wv * 4 + (lane >> 4);
        const int k0 = lane & 15;
        float vals[48];
        float s = 0.f, s2 = 0.f;
        #pragma unroll
        for (int j = 0; j < 48; ++j) {
            float v = H1t[(k0 + 16 * j) * 16 + r];
            vals[j] = v; s += v; s2 += v * v;
        }
        #pragma unroll
        for (int m = 1; m <= 8; m <<= 1) {
            s  += __shfl_xor(s,  m, 64);
            s2 += __shfl_xor(s2, m, 64);
        }
        float mu   = s / 768.f;
        float var  = s2 / 768.f - mu * mu;
        float rstd = rsqrtf(var + 1e-5f);
        #pragma unroll
        for (int j = 0; j < 48; ++j) {
            int k = k0 + 16 * j;
            float v = (vals[j] - mu) * rstd * g1[k] + be1[k];
            v = 0.5f * v * (1.0f + erff(v * 0.70710678118654752f)); // exact gelu
            H1t[k * 16 + r] = v;
        }
    }
    __syncthreads();

    // phase 3: H = H1g @ W2 + b2 ; thread t owns col t, rows 0..15
    float acc[16];
    {
        float b2v = b2[t];
        #pragma unroll
        for (int r = 0; r < 16; ++r) acc[r] = b2v;
    }
    #pragma unroll 2
    for (int k = 0; k < D_HID; ++k) {
        float w = W2[k * D_OUT + t];
        const float4* hp = (const float4*)&H1t[k * 16];
        float4 ha = hp[0], hb = hp[1], hc = hp[2], hd = hp[3];
        float hs[16];
        hs[0]=ha.x; hs[1]=ha.y; hs[2]=ha.z; hs[3]=ha.w;
        hs[4]=hb.x; hs[5]=hb.y; hs[6]=hb.z; hs[7]=hb.w;
        hs[8]=hc.x; hs[9]=hc.y; hs[10]=hc.z; hs[11]=hc.w;
        hs[12]=hd.x; hs[13]=hd.y; hs[14]=hd.z; hs[15]=hd.w;
        #pragma unroll
        for (int r = 0; r < 16; ++r) acc[r] += hs[r] * w;
    }
    #pragma unroll
    for (int r = 0; r < 16; ++r)
        H[(size_t)(row0 + r) * D_OUT + t] = acc[r];
}

// ---------------------------------------------------------------------------
// CSR build: degree histogram -> exclusive scan -> edge-id fill.
// Replaces 410M fp32 atomics with 3.2M int atomics.
// ---------------------------------------------------------------------------
__global__ __launch_bounds__(256) void hist_kernel(
    const int* __restrict__ edges, int* __restrict__ deg)
{
    int e = blockIdx.x * 256 + threadIdx.x;
    atomicAdd(&deg[edges[N_EDGES + e]], 1);
}

__global__ __launch_bounds__(1024) void scan_kernel(
    const int* __restrict__ deg, int* __restrict__ rowptr,
    int* __restrict__ cursor)
{
    __shared__ int sums[1024];
    const int t = threadIdx.x;
    const int CH = (N_NODES + 1023) / 1024;  // 98
    int start = t * CH;
    int end = start + CH; if (end > N_NODES) end = N_NODES;
    int s = 0;
    for (int j = start; j < end; ++j) s += deg[j];
    sums[t] = s;
    __syncthreads();
    // Hillis-Steele inclusive scan over 1024 partials
    for (int off = 1; off < 1024; off <<= 1) {
        int v = (t >= off) ? sums[t - off] : 0;
        __syncthreads();
        sums[t] += v;
        __syncthreads();
    }
    int run = sums[t] - s;  // exclusive prefix for this chunk
    for (int j = start; j < end; ++j) {
        rowptr[j] = run;
        cursor[j] = run;
        run += deg[j];
    }
    if (start < N_NODES && end == N_NODES) rowptr[N_NODES] = run;
}

__global__ __launch_bounds__(256) void fill_kernel(
    const int* __restrict__ edges, int* __restrict__ cursor,
    int* __restrict__ eid)
{
    int e = blockIdx.x * 256 + threadIdx.x;
    int d = edges[N_EDGES + e];
    int pos = atomicAdd(&cursor[d], 1);
    eid[pos] = edges[e];  // src node of this edge
}

// ---------------------------------------------------------------------------
// K3: fused aggregation + finalize:
//   mean = gather-sum(H[src])/max(cnt,1); sage = mean@Wl + bl + h@Wr;
//   out = LN(h + sage) * g2 + be2.
// 16 rows per block, 256 threads; thread t owns dim t: walks each row's CSR
// list with coalesced 1KB-per-edge reads (H is 102MB -> L3-resident),
// depositing mean/h directly in the transposed [k][r] LDS layout.
// ---------------------------------------------------------------------------
__global__ __launch_bounds__(256) void aggfin_kernel(
    const float* __restrict__ H, const int* __restrict__ rowptr,
    const int* __restrict__ eid,
    const float* __restrict__ Wl, const float* __restrict__ bl,
    const float* __restrict__ Wr, const float* __restrict__ g2,
    const float* __restrict__ be2, float* __restrict__ out)
{
    __shared__ float mt[D_OUT * 16];   // mean, [k][r] stride 16
    __shared__ float ht[D_OUT * 16];   // h,    [k][r] stride 16
    __shared__ float red[16 * 4 * 2];
    const int t = threadIdx.x;
    const int row0 = blockIdx.x * 16;

    #pragma unroll 1
    for (int r = 0; r < 16; ++r) {
        const int n = row0 + r;
        const int start = rowptr[n], end = rowptr[n + 1];
        float acc = 0.f;
        int e = start;
        for (; e + 4 <= end; e += 4) {
            int s0 = eid[e], s1 = eid[e + 1], s2 = eid[e + 2], s3 = eid[e + 3];
            float v0 = H[(size_t)s0 * D_OUT + t];
            float v1 = H[(size_t)s1 * D_OUT + t];
            float v2 = H[(size_t)s2 * D_OUT + t];
            float v3 = H[(size_t)s3 * D_OUT + t];
            acc += v0 + v1 + v2 + v3;
        }
        for (; e < end; ++e) acc += H[(size_t)eid[e] * D_OUT + t];
        float inv = (end > start) ? 1.0f / (float)(end - start) : 1.0f;
        mt[t * 16 + r] = acc * inv;
        ht[t * 16 + r] = H[(size_t)n * D_OUT + t];
    }
    __syncthreads();

    float acc[16];
    {
        float blv = bl[t];
        #pragma unroll
        for (int r = 0; r < 16; ++r) acc[r] = blv;
    }
    #pragma unroll 2
    for (int k = 0; k < D_OUT; ++k) {
        float wl = Wl[k * D_OUT + t];
        float wr = Wr[k * D_OUT + t];
        const float4* mp = (const float4*)&mt[k * 16];
        const float4* hp = (const float4*)&ht[k * 16];
        float4 ma = mp[0], mb = mp[1], mc = mp[2], md = mp[3];
        float4 ha = hp[0], hb = hp[1], hc = hp[2], hd = hp[3];
        float ms[16], hs[16];
        ms[0]=ma.x; ms[1]=ma.y; ms[2]=ma.z; ms[3]=ma.w;
        ms[4]=mb.x; ms[5]=mb.y; ms[6]=mb.z; ms[7]=mb.w;
        ms[8]=mc.x; ms[9]=mc.y; ms[10]=mc.z; ms[11]=mc.w;
        ms[12]=md.x; ms[13]=md.y; ms[14]=md.z; ms[15]=md.w;
        hs[0]=ha.x; hs[1]=ha.y; hs[2]=ha.z; hs[3]=ha.w;
        hs[4]=hb.x; hs[5]=hb.y; hs[6]=hb.z; hs[7]=hb.w;
        hs[8]=hc.x; hs[9]=hc.y; hs[10]=hc.z; hs[11]=hc.w;
        hs[12]=hd.x; hs[13]=hd.y; hs[14]=hd.z; hs[15]=hd.w;
        #pragma unroll
        for (int r = 0; r < 16; ++r) acc[r] += ms[r] * wl + hs[r] * wr;
    }

    // y = h + sage; per-row LayerNorm across the 256 threads
    float y[16];
    #pragma unroll
    for (int r = 0; r < 16; ++r) y[r] = ht[t * 16 + r] + acc[r];

    const int lane = t & 63, wv = t >> 6;
    #pragma unroll
    for (int r = 0; r < 16; ++r) {
        float s = y[r], s2 = y[r] * y[r];
        #pragma unroll
        for (int m = 1; m <= 32; m <<= 1) {
            s  += __shfl_xor(s,  m, 64);
            s2 += __shfl_xor(s2, m, 64);
        }
        if (lane == 0) { red[r * 8 + wv * 2] = s; red[r * 8 + wv * 2 + 1] = s2; }
    }
    __syncthreads();

    #pragma unroll
    for (int r = 0; r < 16; ++r) {
        float ssum  = red[r * 8 + 0] + red[r * 8 + 2] + red[r * 8 + 4] + red[r * 8 + 6];
        float ssum2 = red[r * 8 + 1] + red[r * 8 + 3] + red[r * 8 + 5] + red[r * 8 + 7];
        float mu   = ssum / 256.f;
        float var  = ssum2 / 256.f - mu * mu;
        float rstd = rsqrtf(var + 1e-5f);
        out[(size_t)(row0 + r) * D_OUT + t] = (y[r] - mu) * rstd * g2[t] + be2[t];
    }
}

extern "C" void kernel_launch(void* const* d_in, const int* in_sizes, int n_in,
                              void* d_out, int out_size, void* d_ws, size_t ws_size,
                              hipStream_t stream)
{
    const float* X   = (const float*)d_in[0];
    const int*   edg = (const int*)  d_in[1];
    const float* W1  = (const float*)d_in[2];
    const float* b1  = (const float*)d_in[3];
    const float* g1  = (const float*)d_in[4];
    const float* be1 = (const float*)d_in[5];
    const float* W2  = (const float*)d_in[6];
    const float* b2  = (const float*)d_in[7];
    const float* Wl  = (const float*)d_in[8];
    const float* bl  = (const float*)d_in[9];
    const float* Wr  = (const float*)d_in[10];
    const float* g2  = (const float*)d_in[11];
    const float* be2 = (const float*)d_in[12];

    float* out = (float*)d_out;

    // workspace layout
    float* H      = (float*)d_ws;                               // 25.6M floats
    char*  p      = (char*)d_ws + (size_t)N_NODES * D_OUT * sizeof(float);
    int*   deg    = (int*)p;             p += (size_t)(N_NODES + 16) * sizeof(int);
    int*   rowptr = (int*)p;             p += (size_t)(N_NODES + 16) * sizeof(int);
    int*   cursor = (int*)p;             p += (size_t)(N_NODES + 16) * sizeof(int);
    int*   eid    = (int*)p;             // N_EDGES ints

    hipMemsetAsync(deg, 0, (size_t)N_NODES * sizeof(int), stream);

    hist_kernel<<<N_EDGES / 256, 256, 0, stream>>>(edg, deg);
    scan_kernel<<<1, 1024, 0, stream>>>(deg, rowptr, cursor);
    fill_kernel<<<N_EDGES / 256, 256, 0, stream>>>(edg, cursor, eid);

    encoder_kernel<<<N_NODES / 16, 256, 0, stream>>>(X, W1, b1, g1, be1, W2, b2, H);
    aggfin_kernel<<<N_NODES / 16, 256, 0, stream>>>(H, rowptr, eid, Wl, bl, Wr, g2, be2, out);
}

// Round 4
// 1465.997 us; speedup vs baseline: 5.8136x; 2.3575x over previous
//
#include <hip/hip_runtime.h>
#include <hip/hip_bf16.h>
#include <math.h>

#define N_NODES 100000
#define N_EDGES 1600000
#define D_IN    384
#define D_HID   768
#define D_OUT   256

typedef unsigned short ushort_t;
typedef __attribute__((ext_vector_type(8))) short bf16x8;
typedef __attribute__((ext_vector_type(4))) float f32x4;

#define MFMA(a, b, c) __builtin_amdgcn_mfma_f32_16x16x32_bf16((a), (b), (c), 0, 0, 0)

__device__ __forceinline__ ushort_t f2bf(float f) {
    unsigned u = __builtin_bit_cast(unsigned, f);
    u += 0x7fffu + ((u >> 16) & 1u);   // RNE
    return (ushort_t)(u >> 16);
}
__device__ __forceinline__ float bf2f(ushort_t h) {
    return __builtin_bit_cast(float, ((unsigned)h) << 16);
}
__device__ __forceinline__ float gelu_f(float x) {
    // tanh-form GELU via hw exp; |err vs exact erf-GELU| <~ 1e-3
    float u = 0.7978845608028654f * (x + 0.044715f * x * x * x);
    float e = __expf(2.f * u);
    float th = 1.f - 2.f / (e + 1.f);
    return 0.5f * x * (1.f + th);
}

// ---------------------------------------------------------------------------
// transpose + fp32->bf16: WT[n*K + k] = bf16(W[k*N + n])
// ---------------------------------------------------------------------------
__global__ __launch_bounds__(256) void transconv_kernel(
    const float* __restrict__ W, ushort_t* __restrict__ WT, int K, int N)
{
    int idx = blockIdx.x * 256 + threadIdx.x;
    if (idx >= K * N) return;
    int n = idx / K, k = idx % K;
    WT[idx] = f2bf(W[(size_t)k * N + n]);
}

// ---------------------------------------------------------------------------
// CSR build
// ---------------------------------------------------------------------------
__global__ __launch_bounds__(256) void hist_kernel(
    const int* __restrict__ edges, int* __restrict__ deg)
{
    int e = blockIdx.x * 256 + threadIdx.x;
    atomicAdd(&deg[edges[N_EDGES + e]], 1);
}

__global__ __launch_bounds__(1024) void scan_kernel(
    const int* __restrict__ deg, int* __restrict__ rowptr,
    int* __restrict__ cursor)
{
    __shared__ int sums[1024];
    const int t = threadIdx.x;
    const int CH = (N_NODES + 1023) / 1024;
    int start = t * CH;
    int end = start + CH; if (end > N_NODES) end = N_NODES;
    int s = 0;
    for (int j = start; j < end; ++j) s += deg[j];
    sums[t] = s;
    __syncthreads();
    for (int off = 1; off < 1024; off <<= 1) {
        int v = (t >= off) ? sums[t - off] : 0;
        __syncthreads();
        sums[t] += v;
        __syncthreads();
    }
    int run = sums[t] - s;
    for (int j = start; j < end; ++j) {
        rowptr[j] = run;
        cursor[j] = run;
        run += deg[j];
    }
    if (start < N_NODES && end == N_NODES) rowptr[N_NODES] = run;
}

__global__ __launch_bounds__(256) void fill_kernel(
    const int* __restrict__ edges, int* __restrict__ cursor,
    int* __restrict__ eid)
{
    int e = blockIdx.x * 256 + threadIdx.x;
    int d = edges[N_EDGES + e];
    int pos = atomicAdd(&cursor[d], 1);
    eid[pos] = edges[e];
}

// ---------------------------------------------------------------------------
// K1: MFMA encoder. 32 rows/block, 4 waves.
//   GEMM1: [32x384]@[384x768] (wave owns 192-col slice, acc[2][12])
//   LN(768)+GELU -> bf16 H1 in LDS
//   GEMM2: [32x768]@[768x256] (wave owns 64-col slice, acc[2][4])
//   H written bf16 via LDS bounce (4x uint4 = 64B per (r,seg) segment!).
// MFMA 16x16x32 layouts (verified m89/m91/m120):
//   A[m=lane&15][k=(lane>>4)*8+j]  (8 contig bf16 from row m)
//   B from W^T row n=lane&15, same k pattern
//   C/D: col(N)=lane&15, row(M)=(lane>>4)*4+reg
// ---------------------------------------------------------------------------
#define BM 32
#define S1 392   // Xs stride (384+8) bf16 -> 784B, 16B-aligned
#define S2 776   // H1s stride (768+8) bf16 -> 1552B, 16B-aligned
#define SO 264   // out-bounce stride (256+8) bf16 -> 528B, 16B-aligned

__global__ __launch_bounds__(256) void encoder_mfma(
    const float* __restrict__ X, const ushort_t* __restrict__ W1T,
    const float* __restrict__ b1, const float* __restrict__ g1,
    const float* __restrict__ be1, const ushort_t* __restrict__ W2T,
    const float* __restrict__ b2, ushort_t* __restrict__ Hbf)
{
    __shared__ __align__(16) ushort_t Xs[BM * S1];
    __shared__ __align__(16) ushort_t H1s[BM * S2];
    __shared__ float redS[BM * 4], redS2[BM * 4];
    __shared__ float muS[BM], rsS[BM];

    const int t = threadIdx.x;
    const int w = t >> 6, lane = t & 63;
    const int q = lane >> 4, mcol = lane & 15;
    const int kq = q * 8;
    const int row0 = blockIdx.x * BM;

    // stage X tile (32 x 384 fp32 -> bf16 LDS)
    {
        const float4* X4 = (const float4*)(X + (size_t)row0 * D_IN);
        for (int i = t; i < BM * (D_IN / 4); i += 256) {
            int r = i / (D_IN / 4), c4 = i % (D_IN / 4);
            float4 v = X4[i];
            ushort_t* p = &Xs[r * S1 + c4 * 4];
            p[0] = f2bf(v.x); p[1] = f2bf(v.y); p[2] = f2bf(v.z); p[3] = f2bf(v.w);
        }
    }
    __syncthreads();

    // ---- GEMM1 ----
    f32x4 acc1[2][12];
    #pragma unroll
    for (int mt = 0; mt < 2; ++mt)
        #pragma unroll
        for (int nt = 0; nt < 12; ++nt)
            acc1[mt][nt] = (f32x4){0.f, 0.f, 0.f, 0.f};

    for (int kk = 0; kk < D_IN; kk += 32) {
        bf16x8 a0 = *(const bf16x8*)&Xs[(0 * 16 + mcol) * S1 + kk + kq];
        bf16x8 a1 = *(const bf16x8*)&Xs[(1 * 16 + mcol) * S1 + kk + kq];
        #pragma unroll
        for (int nt = 0; nt < 12; ++nt) {
            int n = w * 192 + nt * 16 + mcol;
            bf16x8 b = *(const bf16x8*)&W1T[(size_t)n * D_IN + kk + kq];
            acc1[0][nt] = MFMA(a0, b, acc1[0][nt]);
            acc1[1][nt] = MFMA(a1, b, acc1[1][nt]);
        }
    }

    // bias b1 (per col, must precede LN stats)
    {
        #pragma unroll
        for (int nt = 0; nt < 12; ++nt) {
            float bv = b1[w * 192 + nt * 16 + mcol];
            #pragma unroll
            for (int mt = 0; mt < 2; ++mt)
                #pragma unroll
                for (int reg = 0; reg < 4; ++reg)
                    acc1[mt][nt][reg] += bv;
        }
    }

    // LN stats: per-row sums over this wave's 192 cols, then cross-wave via LDS
    #pragma unroll
    for (int mt = 0; mt < 2; ++mt) {
        #pragma unroll
        for (int reg = 0; reg < 4; ++reg) {
            float s = 0.f, s2 = 0.f;
            #pragma unroll
            for (int nt = 0; nt < 12; ++nt) {
                float v = acc1[mt][nt][reg];
                s += v; s2 += v * v;
            }
            #pragma unroll
            for (int m = 1; m <= 8; m <<= 1) {
                s  += __shfl_xor(s,  m, 64);
                s2 += __shfl_xor(s2, m, 64);
            }
            if (mcol == 0) {
                int row = mt * 16 + q * 4 + reg;
                redS[row * 4 + w] = s;
                redS2[row * 4 + w] = s2;
            }
        }
    }
    __syncthreads();
    if (t < BM) {
        float s  = redS[t * 4] + redS[t * 4 + 1] + redS[t * 4 + 2] + redS[t * 4 + 3];
        float s2 = redS2[t * 4] + redS2[t * 4 + 1] + redS2[t * 4 + 2] + redS2[t * 4 + 3];
        float mu = s / 768.f;
        float var = s2 / 768.f - mu * mu;
        muS[t] = mu;
        rsS[t] = rsqrtf(var + 1e-5f);
    }
    __syncthreads();

    // LN + GELU -> bf16 H1s
    {
        float g1v[12], be1v[12];
        #pragma unroll
        for (int nt = 0; nt < 12; ++nt) {
            int c = w * 192 + nt * 16 + mcol;
            g1v[nt] = g1[c]; be1v[nt] = be1[c];
        }
        #pragma unroll
        for (int mt = 0; mt < 2; ++mt) {
            #pragma unroll
            for (int reg = 0; reg < 4; ++reg) {
                int row = mt * 16 + q * 4 + reg;
                float mu = muS[row], rs = rsS[row];
                #pragma unroll
                for (int nt = 0; nt < 12; ++nt) {
                    float v = (acc1[mt][nt][reg] - mu) * rs * g1v[nt] + be1v[nt];
                    H1s[row * S2 + w * 192 + nt * 16 + mcol] = f2bf(gelu_f(v));
                }
            }
        }
    }
    __syncthreads();

    // ---- GEMM2 ----
    f32x4 acc2[2][4];
    #pragma unroll
    for (int mt = 0; mt < 2; ++mt)
        #pragma unroll
        for (int nt = 0; nt < 4; ++nt)
            acc2[mt][nt] = (f32x4){0.f, 0.f, 0.f, 0.f};

    for (int kk = 0; kk < D_HID; kk += 32) {
        bf16x8 a0 = *(const bf16x8*)&H1s[(0 * 16 + mcol) * S2 + kk + kq];
        bf16x8 a1 = *(const bf16x8*)&H1s[(1 * 16 + mcol) * S2 + kk + kq];
        #pragma unroll
        for (int nt = 0; nt < 4; ++nt) {
            int n = w * 64 + nt * 16 + mcol;
            bf16x8 b = *(const bf16x8*)&W2T[(size_t)n * D_HID + kk + kq];
            acc2[0][nt] = MFMA(a0, b, acc2[0][nt]);
            acc2[1][nt] = MFMA(a1, b, acc2[1][nt]);
        }
    }

    // epilogue: +b2, bf16, bounce via LDS (reuse Xs) for coalesced stores
    ushort_t* Ox = Xs;  // 32*264 <= 32*392
    {
        #pragma unroll
        for (int nt = 0; nt < 4; ++nt) {
            int col = w * 64 + nt * 16 + mcol;
            float bv = b2[col];
            #pragma unroll
            for (int mt = 0; mt < 2; ++mt)
                #pragma unroll
                for (int reg = 0; reg < 4; ++reg) {
                    int row = mt * 16 + q * 4 + reg;
                    Ox[row * SO + col] = f2bf(acc2[mt][nt][reg] + bv);
                }
        }
    }
    __syncthreads();
    {
        // 32 rows x 8 segs; each seg = 32 bf16 = 64B = FOUR uint4
        int r = t >> 3, seg = t & 7;
        const uint4* src = (const uint4*)&Ox[r * SO + seg * 32];
        uint4* dst = (uint4*)&Hbf[(size_t)(row0 + r) * D_OUT + seg * 32];
        #pragma unroll
        for (int j = 0; j < 4; ++j) dst[j] = src[j];
    }
}

// ---------------------------------------------------------------------------
// K2: fused aggregation + dual-MFMA + residual + LN. 16 rows/block, 4 waves.
// ---------------------------------------------------------------------------
#define SA 264   // (256+8) bf16

__global__ __launch_bounds__(256) void aggfin_mfma(
    const ushort_t* __restrict__ Hbf, const int* __restrict__ rowptr,
    const int* __restrict__ eid,
    const ushort_t* __restrict__ WlT, const float* __restrict__ bl,
    const ushort_t* __restrict__ WrT, const float* __restrict__ g2,
    const float* __restrict__ be2, float* __restrict__ out)
{
    __shared__ __align__(16) ushort_t Ma[16 * SA];
    __shared__ __align__(16) ushort_t Ha[16 * SA];
    __shared__ float redS[16 * 4], redS2[16 * 4], muS[16], rsS[16];

    const int t = threadIdx.x;
    const int w = t >> 6, lane = t & 63;
    const int q = lane >> 4, mcol = lane & 15;
    const int kq = q * 8;
    const int row0 = blockIdx.x * 16;

    // gather: mean over neighbors, per dim t
    #pragma unroll 1
    for (int r = 0; r < 16; ++r) {
        int n = row0 + r;
        int start = rowptr[n], end = rowptr[n + 1];
        float acc = 0.f;
        int e = start;
        for (; e + 4 <= end; e += 4) {
            int s0 = eid[e], s1 = eid[e + 1], s2 = eid[e + 2], s3 = eid[e + 3];
            acc += bf2f(Hbf[(size_t)s0 * D_OUT + t]) + bf2f(Hbf[(size_t)s1 * D_OUT + t])
                 + bf2f(Hbf[(size_t)s2 * D_OUT + t]) + bf2f(Hbf[(size_t)s3 * D_OUT + t]);
        }
        for (; e < end; ++e) acc += bf2f(Hbf[(size_t)eid[e] * D_OUT + t]);
        float inv = (end > start) ? 1.f / (float)(end - start) : 1.f;
        Ma[r * SA + t] = f2bf(acc * inv);
        Ha[r * SA + t] = Hbf[(size_t)n * D_OUT + t];
    }
    __syncthreads();

    // dual MFMA: sage = mean@Wl + h@Wr  (M=16, N=256, K=256)
    f32x4 acc[4];
    #pragma unroll
    for (int nt = 0; nt < 4; ++nt) acc[nt] = (f32x4){0.f, 0.f, 0.f, 0.f};

    for (int kk = 0; kk < D_OUT; kk += 32) {
        bf16x8 am = *(const bf16x8*)&Ma[mcol * SA + kk + kq];
        bf16x8 ah = *(const bf16x8*)&Ha[mcol * SA + kk + kq];
        #pragma unroll
        for (int nt = 0; nt < 4; ++nt) {
            int n = w * 64 + nt * 16 + mcol;
            bf16x8 bL = *(const bf16x8*)&WlT[(size_t)n * D_OUT + kk + kq];
            bf16x8 bR = *(const bf16x8*)&WrT[(size_t)n * D_OUT + kk + kq];
            acc[nt] = MFMA(am, bL, acc[nt]);
            acc[nt] = MFMA(ah, bR, acc[nt]);
        }
    }

    // y = h + sage + bl ; LN over 256 cols
    float y[4][4];
    {
        #pragma unroll
        for (int nt = 0; nt < 4; ++nt) {
            int col = w * 64 + nt * 16 + mcol;
            float bv = bl[col];
            #pragma unroll
            for (int reg = 0; reg < 4; ++reg) {
                int row = q * 4 + reg;
                y[nt][reg] = acc[nt][reg] + bv + bf2f(Ha[row * SA + col]);
            }
        }
    }
    #pragma unroll
    for (int reg = 0; reg < 4; ++reg) {
        float s = 0.f, s2 = 0.f;
        #pragma unroll
        for (int nt = 0; nt < 4; ++nt) { float v = y[nt][reg]; s += v; s2 += v * v; }
        #pragma unroll
        for (int m = 1; m <= 8; m <<= 1) {
            s  += __shfl_xor(s,  m, 64);
            s2 += __shfl_xor(s2, m, 64);
        }
        if (mcol == 0) {
            int row = q * 4 + reg;
            redS[row * 4 + w] = s;
            redS2[row * 4 + w] = s2;
        }
    }
    __syncthreads();
    if (t < 16) {
        float s  = redS[t * 4] + redS[t * 4 + 1] + redS[t * 4 + 2] + redS[t * 4 + 3];
        float s2 = redS2[t * 4] + redS2[t * 4 + 1] + redS2[t * 4 + 2] + redS2[t * 4 + 3];
        float mu = s / 256.f;
        float var = s2 / 256.f - mu * mu;
        muS[t] = mu;
        rsS[t] = rsqrtf(var + 1e-5f);
    }
    __syncthreads();
    {
        #pragma unroll
        for (int nt = 0; nt < 4; ++nt) {
            int col = w * 64 + nt * 16 + mcol;
            float gv = g2[col], bv = be2[col];
            #pragma unroll
            for (int reg = 0; reg < 4; ++reg) {
                int row = q * 4 + reg;
                out[(size_t)(row0 + row) * D_OUT + col] =
                    (y[nt][reg] - muS[row]) * rsS[row] * gv + bv;
            }
        }
    }
}

extern "C" void kernel_launch(void* const* d_in, const int* in_sizes, int n_in,
                              void* d_out, int out_size, void* d_ws, size_t ws_size,
                              hipStream_t stream)
{
    const float* X   = (const float*)d_in[0];
    const int*   edg = (const int*)  d_in[1];
    const float* W1  = (const float*)d_in[2];
    const float* b1  = (const float*)d_in[3];
    const float* g1  = (const float*)d_in[4];
    const float* be1 = (const float*)d_in[5];
    const float* W2  = (const float*)d_in[6];
    const float* b2  = (const float*)d_in[7];
    const float* Wl  = (const float*)d_in[8];
    const float* bl  = (const float*)d_in[9];
    const float* Wr  = (const float*)d_in[10];
    const float* g2  = (const float*)d_in[11];
    const float* be2 = (const float*)d_in[12];

    float* out = (float*)d_out;

    // workspace layout (all 16B aligned)
    char* p = (char*)d_ws;
    ushort_t* Hbf = (ushort_t*)p;  p += (size_t)N_NODES * D_OUT * sizeof(ushort_t); // 51.2MB
    ushort_t* W1T = (ushort_t*)p;  p += (size_t)D_HID * D_IN * sizeof(ushort_t);
    ushort_t* W2T = (ushort_t*)p;  p += (size_t)D_OUT * D_HID * sizeof(ushort_t);
    ushort_t* WlT = (ushort_t*)p;  p += (size_t)D_OUT * D_OUT * sizeof(ushort_t);
    ushort_t* WrT = (ushort_t*)p;  p += (size_t)D_OUT * D_OUT * sizeof(ushort_t);
    int* deg    = (int*)p;         p += (size_t)(N_NODES + 16) * sizeof(int);
    int* rowptr = (int*)p;         p += (size_t)(N_NODES + 16) * sizeof(int);
    int* cursor = (int*)p;         p += (size_t)(N_NODES + 16) * sizeof(int);
    int* eid    = (int*)p;

    hipMemsetAsync(deg, 0, (size_t)N_NODES * sizeof(int), stream);

    // weight prep (bf16 transposes)
    transconv_kernel<<<(D_IN * D_HID + 255) / 256, 256, 0, stream>>>(W1, W1T, D_IN, D_HID);
    transconv_kernel<<<(D_HID * D_OUT + 255) / 256, 256, 0, stream>>>(W2, W2T, D_HID, D_OUT);
    transconv_kernel<<<(D_OUT * D_OUT + 255) / 256, 256, 0, stream>>>(Wl, WlT, D_OUT, D_OUT);
    transconv_kernel<<<(D_OUT * D_OUT + 255) / 256, 256, 0, stream>>>(Wr, WrT, D_OUT, D_OUT);

    // CSR build
    hist_kernel<<<N_EDGES / 256, 256, 0, stream>>>(edg, deg);
    scan_kernel<<<1, 1024, 0, stream>>>(deg, rowptr, cursor);
    fill_kernel<<<N_EDGES / 256, 256, 0, stream>>>(edg, cursor, eid);

    // main pipeline
    encoder_mfma<<<N_NODES / BM, 256, 0, stream>>>(X, W1T, b1, g1, be1, W2T, b2, Hbf);
    aggfin_mfma<<<N_NODES / 16, 256, 0, stream>>>(Hbf, rowptr, eid, WlT, bl, WrT, g2, be2, out);
}